// Round 4
// baseline (115.552 us; speedup 1.0000x reference)
//
#include <hip/hip_runtime.h>

// Grouped GEMM a[16384,512] x b[8][512,512] (fp32, groups of 2048 rows) -> fp32.
// Single fused kernel: 128x128 tile, BK=32, fp32->bf16 cvt in staging (cvt VALU
// is ~0.4us chip-wide - negligible), mfma_f32_16x16x32_bf16, fp32 accum.
// R4: BK=32 + launch_bounds(256,3) -> 40KB LDS, ~3 blocks/CU (12 waves/CU) for
// latency cover; XCD swizzle co-locates the 4 tn-siblings of each tm on one XCD
// (A tile: 1 HBM fetch + 3 L2 hits; per-XCD B[g]=1MB and A slice=4MB L2-resident);
// register pipeline with prefetch issued AFTER the barrier (not drained by it).

#define KDIM 512
#define NDIM 512
#define BM 128
#define BN 128
#define BK 32
#define LDST 40   // 32 + 8 pad bf16: 80 B rows, 16-B aligned for b128 ops

typedef __bf16 bf16x8 __attribute__((ext_vector_type(8)));
typedef __bf16 bf16x4 __attribute__((ext_vector_type(4)));
typedef float  f32x4  __attribute__((ext_vector_type(4)));

__global__ __launch_bounds__(256, 3)
void grouped_gemm_kernel(const float* __restrict__ A,
                         const float* __restrict__ B,
                         const int*   __restrict__ glist,
                         float*       __restrict__ C,
                         int M, int G)
{
    __shared__ __bf16 As[2][BM * LDST];   // 2 x 10 KiB
    __shared__ __bf16 Bs[2][BN * LDST];   // 2 x 10 KiB  (40 KiB total)

    // XCD-aware swizzle (blk%8 -> XCD round-robin heuristic, perf-only):
    // the 4 tn-siblings of one tm land on the same XCD.
    const int b   = blockIdx.x;
    const int xcd = b & 7;
    const int i   = b >> 3;
    const int tm  = xcd * 16 + (i >> 2);   // 128 tm values, 16 per XCD
    const int tn  = i & 3;
    const int row0 = tm * BM;
    const int col0 = tn * BN;

    // searchsorted(group_list, row0, side='right'); tiles never straddle groups
    int gid = 0;
    for (int g = 0; g < G; ++g) gid += (glist[g] <= row0) ? 1 : 0;
    const float* Bg = B + (size_t)gid * KDIM * NDIM;

    const int t    = threadIdx.x;
    const int lane = t & 63;
    const int wave = t >> 6;
    const int lm   = lane & 15;
    const int quad = lane >> 4;
    const int wm   = wave >> 1;
    const int wn   = wave & 1;

    // A staging: thread covers 16 contiguous k of one row (half-row)
    const int ar  = t >> 1;            // 0..127
    const int akh = (t & 1) * 16;      // 0 or 16
    // B staging: thread covers 4 k-rows x 4 n-cols
    const int bk0 = (t >> 5) * 4;      // 0..28
    const int bn0 = (t & 31) * 4;      // 0..124

    const float* aptr = A + (size_t)(row0 + ar) * KDIM + akh;
    const float* bptr = Bg + (size_t)bk0 * NDIM + col0 + bn0;

    f32x4 ra[4], rb[4];

    // ---- prologue: K-tile 0 into registers ----
#pragma unroll
    for (int s = 0; s < 4; ++s) ra[s] = *(const f32x4*)(aptr + s * 4);
#pragma unroll
    for (int dk = 0; dk < 4; ++dk) rb[dk] = *(const f32x4*)(bptr + (size_t)dk * NDIM);

    f32x4 acc[4][4];
#pragma unroll
    for (int ii = 0; ii < 4; ++ii)
#pragma unroll
        for (int j = 0; j < 4; ++j)
            acc[ii][j] = (f32x4){0.f, 0.f, 0.f, 0.f};

    const int NITER = KDIM / BK;       // 16
    for (int it = 0; it < NITER; ++it) {
        __bf16* as = As[it & 1];
        __bf16* bs = Bs[it & 1];

        // ---- cvt + stage A (vmcnt wait lands here) ----
        {
            bf16x8 w0, w1;
            w0[0] = (__bf16)ra[0][0]; w0[1] = (__bf16)ra[0][1];
            w0[2] = (__bf16)ra[0][2]; w0[3] = (__bf16)ra[0][3];
            w0[4] = (__bf16)ra[1][0]; w0[5] = (__bf16)ra[1][1];
            w0[6] = (__bf16)ra[1][2]; w0[7] = (__bf16)ra[1][3];
            w1[0] = (__bf16)ra[2][0]; w1[1] = (__bf16)ra[2][1];
            w1[2] = (__bf16)ra[2][2]; w1[3] = (__bf16)ra[2][3];
            w1[4] = (__bf16)ra[3][0]; w1[5] = (__bf16)ra[3][1];
            w1[6] = (__bf16)ra[3][2]; w1[7] = (__bf16)ra[3][3];
            *(bf16x8*)&as[ar * LDST + akh]     = w0;
            *(bf16x8*)&as[ar * LDST + akh + 8] = w1;
        }
        // ---- cvt + stage B transposed [n][k], 16B-granule XOR swizzle ----
#pragma unroll
        for (int dn = 0; dn < 4; ++dn) {
            const int n = bn0 + dn;
            bf16x4 w;
#pragma unroll
            for (int dk = 0; dk < 4; ++dk) w[dk] = (__bf16)rb[dk][dn];
            const int g16  = bk0 >> 3;          // 0..3
            const int half = (bk0 >> 2) & 1;
            const int phys = g16 ^ ((n >> 3) & 3);
            *(bf16x4*)&bs[n * LDST + phys * 8 + half * 4] = w;
        }

        __syncthreads();

        // ---- prefetch next K-tile AFTER the barrier ----
        if (it < NITER - 1) {
            const int kb = (it + 1) * BK;
#pragma unroll
            for (int s = 0; s < 4; ++s)
                ra[s] = *(const f32x4*)(aptr + kb + s * 4);
#pragma unroll
            for (int dk = 0; dk < 4; ++dk)
                rb[dk] = *(const f32x4*)(bptr + (size_t)(kb + dk) * NDIM);
        }

        // ---- fragments + 16 MFMAs (one k-step of 32) ----
        {
            bf16x8 af[4], bfr[4];
#pragma unroll
            for (int ii = 0; ii < 4; ++ii)
                af[ii] = *(const bf16x8*)&as[(wm * 64 + ii * 16 + lm) * LDST + quad * 8];
#pragma unroll
            for (int j = 0; j < 4; ++j) {
                const int n = wn * 64 + j * 16 + lm;
                const int phys = quad ^ ((n >> 3) & 3);
                bfr[j] = *(const bf16x8*)&bs[n * LDST + phys * 8];
            }
#pragma unroll
            for (int ii = 0; ii < 4; ++ii)
#pragma unroll
                for (int j = 0; j < 4; ++j)
                    acc[ii][j] = __builtin_amdgcn_mfma_f32_16x16x32_bf16(
                        af[ii], bfr[j], acc[ii][j], 0, 0, 0);
        }
        // next iter writes the other buffer; reuse ordered by next barrier
    }

    // ---- epilogue: C/D layout col=lane&15, row=quad*4+reg ----
#pragma unroll
    for (int ii = 0; ii < 4; ++ii) {
        const int gr0 = row0 + wm * 64 + ii * 16 + quad * 4;
#pragma unroll
        for (int j = 0; j < 4; ++j) {
            const int gc = col0 + wn * 64 + j * 16 + lm;
#pragma unroll
            for (int r = 0; r < 4; ++r)
                C[(size_t)(gr0 + r) * NDIM + gc] = acc[ii][j][r];
        }
    }
}

extern "C" void kernel_launch(void* const* d_in, const int* in_sizes, int n_in,
                              void* d_out, int out_size, void* d_ws, size_t ws_size,
                              hipStream_t stream) {
    const float* a  = (const float*)d_in[0];
    const float* bw = (const float*)d_in[1];
    const int*   gl = (const int*)d_in[2];
    float* out = (float*)d_out;

    const int M = in_sizes[0] / KDIM;          // 16384
    const int G = in_sizes[2];                 // 8

    dim3 grid((M / BM) * (NDIM / BN));         // 512 blocks
    grouped_gemm_kernel<<<grid, 256, 0, stream>>>(a, bw, gl, out, M, G);
}